// Round 2
// baseline (842.547 us; speedup 1.0000x reference)
//
#include <hip/hip_runtime.h>

typedef __bf16 bf16_t;
typedef __attribute__((ext_vector_type(8))) __bf16 bf16x8;
typedef __attribute__((ext_vector_type(4))) float f32x4;

static constexpr int Lc = 2, NEc = 4, Hc = 768, FFc = 3072, NHc = 12;
static constexpr int Bc = 8, Tc = 2048;

__device__ __forceinline__ void gll16(const bf16_t* g, bf16_t* l) {
  __builtin_amdgcn_global_load_lds(
      (const __attribute__((address_space(1))) void*)g,
      (__attribute__((address_space(3))) void*)l, 16, 0, 0);
}

// ---------------------------------------------------------------- route
__global__ __launch_bounds__(256) void route_k(const int* __restrict__ ntp,
                                               int* __restrict__ perm,
                                               int* __restrict__ offs) {
  __shared__ int cnt[NEc];
  __shared__ int base[NEc];
  int tid = threadIdx.x;
  if (tid < NEc) cnt[tid] = 0;
  __syncthreads();
  for (int t = tid; t < Tc; t += 256) atomicAdd(&cnt[ntp[t]], 1);
  __syncthreads();
  if (tid == 0) {
    int a = 0;
    for (int e = 0; e < NEc; ++e) { base[e] = a; offs[e] = a; a += cnt[e]; }
    offs[NEc] = a;
  }
  __syncthreads();
  for (int t = tid; t < Tc; t += 256) {
    int e = ntp[t];
    int p = atomicAdd(&base[e], 1);
    perm[p] = t;
  }
}

// ---------------------------------------------------------------- PE add
__global__ __launch_bounds__(256) void pe_add(const float* __restrict__ xin,
                                              float* __restrict__ x0) {
  int p = blockIdx.x * 256 + threadIdx.x;
  int t = p / 384;
  int jj = p - t * 384;
  int s = t & 255;
  float ang = (float)s * __expf((float)jj * -0.0239852613894f);
  float sn, cs;
  sincosf(ang, &sn, &cs);
  float2 xv = ((const float2*)xin)[p];
  float2 o;  o.x = xv.x + sn;  o.y = xv.y + cs;
  ((float2*)x0)[p] = o;
}

// ---------------------------------------------------------------- LayerNorm
__global__ __launch_bounds__(256) void ln_k(const float* __restrict__ x,
                                            const float* __restrict__ g,
                                            const float* __restrict__ bb,
                                            bf16_t* __restrict__ out) {
  int w = threadIdx.x >> 6, lane = threadIdx.x & 63;
  int t = blockIdx.x * 4 + w;
  const float4* xr = (const float4*)(x + (size_t)t * Hc);
  float4 v[3];
  float s = 0.f, s2 = 0.f;
  for (int i = 0; i < 3; ++i) {
    v[i] = xr[lane + i * 64];
    s  += v[i].x + v[i].y + v[i].z + v[i].w;
    s2 += v[i].x * v[i].x + v[i].y * v[i].y + v[i].z * v[i].z + v[i].w * v[i].w;
  }
  for (int o = 1; o < 64; o <<= 1) { s += __shfl_xor(s, o); s2 += __shfl_xor(s2, o); }
  float mu = s * (1.f / 768.f);
  float r = rsqrtf(s2 * (1.f / 768.f) - mu * mu + 1e-5f);
  bf16_t* orow = out + (size_t)t * Hc;
  for (int i = 0; i < 3; ++i) {
    int i4 = lane + i * 64;
    float4 gg = ((const float4*)g)[i4];
    float4 b4 = ((const float4*)bb)[i4];
    union { bf16_t h[4]; uint2 u; } pk;
    pk.h[0] = (bf16_t)((v[i].x - mu) * r * gg.x + b4.x);
    pk.h[1] = (bf16_t)((v[i].y - mu) * r * gg.y + b4.y);
    pk.h[2] = (bf16_t)((v[i].z - mu) * r * gg.z + b4.z);
    pk.h[3] = (bf16_t)((v[i].w - mu) * r * gg.w + b4.w);
    ((uint2*)orow)[i4] = pk.u;
  }
}

// ---------------------------------------------------------------- transpose+convert fp32 [K,N] -> bf16 [N,K]
__global__ __launch_bounds__(256) void tconv(const float* __restrict__ s0,
                                             const float* __restrict__ s1,
                                             const float* __restrict__ s2,
                                             long sstride,
                                             bf16_t* __restrict__ dst, long dstride,
                                             int K, int N) {
  int z = blockIdx.z;
  const float* src = (sstride == 0) ? (z == 0 ? s0 : (z == 1 ? s1 : s2)) : (s0 + (size_t)z * sstride);
  bf16_t* d = dst + (size_t)z * dstride;
  int n0 = blockIdx.x * 64, k0 = blockIdx.y * 64;
  __shared__ float tl[64][65];
  int c = threadIdx.x & 63, r0 = threadIdx.x >> 6;
  for (int i = 0; i < 16; ++i) {
    int r = r0 + i * 4;
    tl[r][c] = src[(size_t)(k0 + r) * N + n0 + c];
  }
  __syncthreads();
  for (int i = 0; i < 16; ++i) {
    int r = r0 + i * 4;
    d[(size_t)(n0 + r) * K + k0 + c] = (bf16_t)tl[c][r];
  }
}

// ---------------------------------------------------------------- GEMM v2 (global_load_lds staging)
// C[M,N] = A[M,K] * Bt[N,K]^T, 128x128 tile, BK=32.
// MODE 0: QKV (out bf16 + range bias)  MODE 1: FFN1 (gather rows, GELU, grouped out)
// MODE 2: FFN2 split-K x4 (atomicAdd into outF)
template <int MODE>
__global__ __launch_bounds__(256) void gemm2(
    const bf16_t* __restrict__ A, const bf16_t* __restrict__ Bt,
    int K, int N, int kIters, long btStride, long biasStride,
    const int* __restrict__ perm, const int* __restrict__ offs,
    const float* __restrict__ bqp, const float* __restrict__ bkp,
    const float* __restrict__ bvp, const float* __restrict__ biasE,
    float* __restrict__ outF, bf16_t* __restrict__ outB) {
  __shared__ bf16_t Ald[128 * 32];
  __shared__ bf16_t Bld[128 * 32];
  int tid = threadIdx.x, lane = tid & 63, w = tid >> 6;
  int quad = lane >> 4, col = lane & 15;
  int m0 = blockIdx.y * 128, n0 = blockIdx.x * 128;
  int e = 0, kStart = 0, off = 0, cnt = Tc;
  if (MODE == 1) e = blockIdx.z;
  if (MODE == 2) { e = blockIdx.z >> 2; kStart = (blockIdx.z & 3) * (K / 4); }
  if (MODE != 0) {
    off = offs[e];
    cnt = offs[e + 1] - off;
    if (m0 >= cnt) return;
  }
  const bf16_t* B0 = Bt + (size_t)e * btStride;

  // staging pointers: wave w covers rows 32w..32w+31 of A and of B (2 instrs of 16 rows)
  const bf16_t* ga[2];
  const bf16_t* gb[2];
  bf16_t* la[2];
  bf16_t* lb[2];
  for (int j = 0; j < 2; ++j) {
    int rbase = 32 * w + 16 * j;
    int row = rbase + (lane >> 2);
    int ch = ((lane & 3) - (row >> 1)) & 3;  // global chunk landing in swizzled slot lane&3
    int gm = m0 + row;
    int gmc = (gm < cnt) ? gm : (cnt - 1);
    int srow;
    if (MODE == 0) srow = gm;
    else if (MODE == 1) srow = perm[off + gmc];
    else srow = off + gmc;
    ga[j] = A + (size_t)srow * K + kStart + ch * 8;
    gb[j] = B0 + (size_t)(n0 + row) * K + kStart + ch * 8;
    la[j] = Ald + rbase * 32;
    lb[j] = Bld + rbase * 32;
  }

  int wr = (w >> 1) * 64, wc = (w & 1) * 64;
  const bf16_t* ar[4];
  const bf16_t* br[4];
  for (int r = 0; r < 4; ++r) {
    int row = wr + r * 16 + col;
    ar[r] = Ald + row * 32 + (((quad + (row >> 1)) & 3) << 3);
  }
  for (int c = 0; c < 4; ++c) {
    int row = wc + c * 16 + col;
    br[c] = Bld + row * 32 + (((quad + (row >> 1)) & 3) << 3);
  }

  const f32x4 z4 = {0.f, 0.f, 0.f, 0.f};
  f32x4 acc[4][4];
  for (int r = 0; r < 4; ++r)
    for (int c = 0; c < 4; ++c) acc[r][c] = z4;

  for (int it = 0; it < kIters; ++it) {
    __syncthreads();
    gll16(ga[0], la[0]);
    gll16(ga[1], la[1]);
    gll16(gb[0], lb[0]);
    gll16(gb[1], lb[1]);
    ga[0] += 32; ga[1] += 32; gb[0] += 32; gb[1] += 32;
    __syncthreads();
    bf16x8 af[4], bv[4];
    for (int r = 0; r < 4; ++r) af[r] = *(const bf16x8*)ar[r];
    for (int c = 0; c < 4; ++c) bv[c] = *(const bf16x8*)br[c];
    for (int r = 0; r < 4; ++r)
      for (int c = 0; c < 4; ++c)
        acc[r][c] = __builtin_amdgcn_mfma_f32_16x16x32_bf16(af[r], bv[c], acc[r][c], 0, 0, 0);
  }

  for (int r = 0; r < 4; ++r)
    for (int c = 0; c < 4; ++c) {
      int mloc = wr + r * 16 + quad * 4;
      int n = n0 + wc + c * 16 + col;
      for (int i = 0; i < 4; ++i) {
        int gm = m0 + mloc + i;
        float av = acc[r][c][i];
        if (MODE == 0) {
          float bias = (n < 768) ? bqp[n] : (n < 1536) ? bkp[n - 768] : bvp[n - 1536];
          outB[(size_t)gm * N + n] = (bf16_t)(av + bias);
        } else if (MODE == 1) {
          if (gm < cnt) {
            float v = av + biasE[(size_t)e * biasStride + n];
            float u = v * (0.7978845608f + 0.0356774081f * v * v);
            float t = 1.f - 2.f / (1.f + __expf(2.f * u));
            outB[(size_t)(off + gm) * N + n] = (bf16_t)(0.5f * v * (1.f + t));
          }
        } else {
          if (gm < cnt) {
            int tok = perm[off + gm];
            atomicAdd(&outF[(size_t)tok * N + n], av);
          }
        }
      }
    }
}

// ---------------------------------------------------------------- x1 = x0 + b2[expert]
__global__ __launch_bounds__(256) void x1init_k(const float* __restrict__ x0,
                                                const float* __restrict__ b2l,
                                                const int* __restrict__ ntp,
                                                float* __restrict__ x1) {
  int i = blockIdx.x * 256 + threadIdx.x;  // float4 index over 2048*192
  int t = i / 192, d = i - t * 192;
  int e = ntp[t];
  float4 a = ((const float4*)x0)[i];
  float4 bb = ((const float4*)(b2l + (size_t)e * Hc))[d];
  a.x += bb.x; a.y += bb.y; a.z += bb.z; a.w += bb.w;
  ((float4*)x1)[i] = a;
}

// ---------------------------------------------------------------- attention
__global__ __launch_bounds__(256) void attn_k(const bf16_t* __restrict__ qkv,
                                              const int* __restrict__ np,
                                              float* __restrict__ x) {
  __shared__ bf16_t Kld[256 * 64];  // reused as P after scores
  __shared__ bf16_t Vt[64 * 256];   // V transposed [d][s], swizzled
  int tid = threadIdx.x, lane = tid & 63, w = tid >> 6;
  int qt = blockIdx.x;
  int b = blockIdx.y / NHc, h = blockIdx.y % NHc;

  // K staging via global_load_lds: row = 128B = 8 lanes; 8 rows/instr; 8 instrs/wave
  for (int j = 0; j < 8; ++j) {
    int rbase = w * 64 + j * 8;
    int row = rbase + (lane >> 3);
    int oc = ((lane & 7) - row) & 7;
    const bf16_t* gp = qkv + ((size_t)(b * 256 + row)) * 2304 + 768 + h * 64 + oc * 8;
    gll16(gp, Kld + rbase * 64);
  }
  // V transpose staging (scalar LDS writes, 2-way max conflicts)
  {
    int s = tid, shi = s >> 3, slo = s & 7;
    const uint4* vs = (const uint4*)(qkv + ((size_t)(b * 256 + s)) * 2304 + 1536 + h * 64);
    for (int cc = 0; cc < 8; ++cc) {
      uint4 pk = vs[cc];
      const bf16_t* pv = (const bf16_t*)&pk;
      for (int jj = 0; jj < 8; ++jj) {
        int d = cc * 8 + jj;
        Vt[d * 256 + ((shi + d) & 31) * 8 + slo] = pv[jj];
      }
    }
  }
  int quad = lane >> 4, col = lane & 15;
  float madd[16];
  for (int nt = 0; nt < 16; ++nt)
    madd[nt] = (np[b * 256 + nt * 16 + col] != 0) ? 0.f : -10000.f;
  int qrow = qt * 64 + w * 16 + col;
  const bf16_t* qb = qkv + ((size_t)(b * 256 + qrow)) * 2304 + h * 64;
  bf16x8 qf0 = *(const bf16x8*)(qb + quad * 8);
  bf16x8 qf1 = *(const bf16x8*)(qb + 32 + quad * 8);
  __syncthreads();

  const f32x4 z4 = {0.f, 0.f, 0.f, 0.f};
  f32x4 sc[16];
  for (int nt = 0; nt < 16; ++nt) {
    int row = nt * 16 + col;
    bf16x8 k0 = *(const bf16x8*)(Kld + row * 64 + (((0 + quad + row) & 7) << 3));
    bf16x8 k1 = *(const bf16x8*)(Kld + row * 64 + (((4 + quad + row) & 7) << 3));
    f32x4 z = z4;
    z = __builtin_amdgcn_mfma_f32_16x16x32_bf16(qf0, k0, z, 0, 0, 0);
    z = __builtin_amdgcn_mfma_f32_16x16x32_bf16(qf1, k1, z, 0, 0, 0);
    sc[nt] = z;
  }
  for (int nt = 0; nt < 16; ++nt) {
    float a = madd[nt];
    sc[nt][0] += a; sc[nt][1] += a; sc[nt][2] += a; sc[nt][3] += a;
  }
  float pm[4], rl[4];
  for (int i = 0; i < 4; ++i) {
    float m = -1e30f;
    for (int nt = 0; nt < 16; ++nt) m = fmaxf(m, sc[nt][i]);
    for (int o = 1; o < 16; o <<= 1) m = fmaxf(m, __shfl_xor(m, o));
    float ssum = 0.f;
    for (int nt = 0; nt < 16; ++nt) ssum += __expf(sc[nt][i] - m);
    for (int o = 1; o < 16; o <<= 1) ssum += __shfl_xor(ssum, o);
    pm[i] = m;
    rl[i] = 1.f / ssum;
  }
  __syncthreads();  // done reading Kld
  bf16_t* Pb = Kld + w * 4096;  // wave's 16 x 256 P tile
  for (int nt = 0; nt < 16; ++nt)
    for (int i = 0; i < 4; ++i) {
      int prow = quad * 4 + i;
      int key = nt * 16 + col;
      Pb[prow * 256 + (((key >> 3) + prow) & 31) * 8 + (key & 7)] =
          (bf16_t)__expf(sc[nt][i] - pm[i]);
    }
  __syncthreads();
  f32x4 oacc[4];
  for (int i = 0; i < 4; ++i) oacc[i] = z4;
  for (int kk2 = 0; kk2 < 8; ++kk2) {
    bf16x8 pa = *(const bf16x8*)(Pb + col * 256 + (((kk2 * 4 + quad + col) & 31) << 3));
    for (int nt2 = 0; nt2 < 4; ++nt2) {
      int d = nt2 * 16 + col;
      bf16x8 bv8 = *(const bf16x8*)(Vt + d * 256 + (((kk2 * 4 + quad + d) & 31) << 3));
      oacc[nt2] = __builtin_amdgcn_mfma_f32_16x16x32_bf16(pa, bv8, oacc[nt2], 0, 0, 0);
    }
  }
  for (int nt2 = 0; nt2 < 4; ++nt2)
    for (int i = 0; i < 4; ++i) {
      size_t o = ((size_t)(b * 256 + qt * 64 + w * 16 + quad * 4 + i)) * Hc + h * 64 + nt2 * 16 + col;
      x[o] += oacc[nt2][i] * rl[i];
    }
}

// ---------------------------------------------------------------- permute via note_pos
__global__ __launch_bounds__(256) void permute_k(const float* __restrict__ xf,
                                                 const int* __restrict__ np,
                                                 float* __restrict__ dst) {
  int i = blockIdx.x * 256 + threadIdx.x;
  int t = i / 192, d = i - t * 192;
  int idx = np[t];
  float4 v;
  if (idx != 0) v = ((const float4*)xf)[(size_t)(idx - 1) * 192 + d];
  else { v.x = v.y = v.z = v.w = 0.f; }
  ((float4*)dst)[i] = v;
}

// ---------------------------------------------------------------- host
extern "C" void kernel_launch(void* const* d_in, const int* in_sizes, int n_in,
                              void* d_out, int out_size, void* d_ws, size_t ws_size,
                              hipStream_t stream) {
  const float* x_in = (const float*)d_in[0];
  const int* note_pos = (const int*)d_in[1];
  const int* ntp = (const int*)d_in[2];
  const float* Wq = (const float*)d_in[3];
  const float* bq = (const float*)d_in[4];
  const float* Wk = (const float*)d_in[5];
  const float* bk = (const float*)d_in[6];
  const float* Wv = (const float*)d_in[7];
  const float* bv = (const float*)d_in[8];
  const float* ln1w = (const float*)d_in[9];
  const float* ln1b = (const float*)d_in[10];
  const float* ln2w = (const float*)d_in[11];
  const float* ln2b = (const float*)d_in[12];
  const float* W1 = (const float*)d_in[13];
  const float* b1 = (const float*)d_in[14];
  const float* W2 = (const float*)d_in[15];
  const float* b2 = (const float*)d_in[16];
  float* out = (float*)d_out;

  char* p = (char*)d_ws;
  auto carve = [&](size_t bytes) -> char* {
    char* r = p;
    p += (bytes + 255) & ~(size_t)255;
    return r;
  };
  float* x0 = (float*)carve((size_t)Tc * Hc * 4);
  float* x1 = (float*)carve((size_t)Tc * Hc * 4);
  bf16_t* h16 = (bf16_t*)carve((size_t)Tc * Hc * 2);
  bf16_t* big = (bf16_t*)carve((size_t)Tc * FFc * 2);  // union: qkv16 / act1
  bf16_t* qkv16 = big;
  bf16_t* act1 = big;
  bf16_t* wqkvt = (bf16_t*)carve((size_t)2304 * 768 * 2);
  bf16_t* w1t = (bf16_t*)carve((size_t)NEc * FFc * Hc * 2);
  bf16_t* w2t = (bf16_t*)carve((size_t)NEc * Hc * FFc * 2);
  int* perm = (int*)carve(Tc * 4);
  int* offs = (int*)carve(64);

  route_k<<<1, 256, 0, stream>>>(ntp, perm, offs);
  pe_add<<<Tc * Hc / 2 / 256, 256, 0, stream>>>(x_in, x0);

  for (int l = 0; l < Lc; ++l) {
    tconv<<<dim3(12, 12, 3), 256, 0, stream>>>(Wq + (size_t)l * Hc * Hc, Wk + (size_t)l * Hc * Hc,
                                               Wv + (size_t)l * Hc * Hc, 0L, wqkvt, (long)Hc * Hc,
                                               Hc, Hc);
    tconv<<<dim3(48, 12, 4), 256, 0, stream>>>(W1 + (size_t)l * NEc * Hc * FFc, nullptr, nullptr,
                                               (long)Hc * FFc, w1t, (long)FFc * Hc, Hc, FFc);
    tconv<<<dim3(12, 48, 4), 256, 0, stream>>>(W2 + (size_t)l * NEc * FFc * Hc, nullptr, nullptr,
                                               (long)FFc * Hc, w2t, (long)Hc * FFc, FFc, Hc);
    ln_k<<<Tc / 4, 256, 0, stream>>>(x0, ln1w + l * Hc, ln1b + l * Hc, h16);
    gemm2<0><<<dim3(18, 16, 1), 256, 0, stream>>>(
        h16, wqkvt, Hc, 2304, 24, 0L, 0L, perm, offs,
        bq + l * Hc, bk + l * Hc, bv + l * Hc, nullptr, nullptr, qkv16);
    attn_k<<<dim3(4, Bc * NHc), 256, 0, stream>>>(qkv16, note_pos, x0);
    ln_k<<<Tc / 4, 256, 0, stream>>>(x0, ln2w + l * Hc, ln2b + l * Hc, h16);
    gemm2<1><<<dim3(24, 16, NEc), 256, 0, stream>>>(
        h16, w1t, Hc, FFc, 24, (long)FFc * Hc, (long)FFc, perm, offs,
        nullptr, nullptr, nullptr, b1 + (size_t)l * NEc * FFc, nullptr, act1);
    x1init_k<<<Tc * 192 / 256, 256, 0, stream>>>(x0, b2 + (size_t)l * NEc * Hc, ntp, x1);
    gemm2<2><<<dim3(6, 16, NEc * 4), 256, 0, stream>>>(
        act1, w2t, FFc, Hc, 24, (long)Hc * FFc, (long)Hc, perm, offs,
        nullptr, nullptr, nullptr, nullptr, x1, nullptr);
    permute_k<<<Tc * 192 / 256, 256, 0, stream>>>(x1, note_pos, (l == Lc - 1) ? out : x0);
  }
}

// Round 3
// 486.461 us; speedup vs baseline: 1.7320x; 1.7320x over previous
//
#include <hip/hip_runtime.h>

typedef __bf16 bf16_t;
typedef __attribute__((ext_vector_type(8))) __bf16 bf16x8;
typedef __attribute__((ext_vector_type(4))) float f32x4;

static constexpr int Lc = 2, NEc = 4, Hc = 768, FFc = 3072, NHc = 12;
static constexpr int Bc = 8, Tc = 2048;

__device__ __forceinline__ void gll16(const bf16_t* g, bf16_t* l) {
  __builtin_amdgcn_global_load_lds(
      (const __attribute__((address_space(1))) void*)g,
      (__attribute__((address_space(3))) void*)l, 16, 0, 0);
}

// ---------------------------------------------------------------- route (1 wave, ballot counting sort)
__global__ __launch_bounds__(64) void route_k(const int* __restrict__ ntp,
                                              int* __restrict__ perm,
                                              int* __restrict__ offs) {
  int lane = threadIdx.x;
  int myE[32];
  int cnt0 = 0, cnt1 = 0, cnt2 = 0, cnt3 = 0;
  for (int c = 0; c < 32; ++c) {
    int e = ntp[c * 64 + lane];
    myE[c] = e;
    cnt0 += __popcll(__ballot(e == 0));
    cnt1 += __popcll(__ballot(e == 1));
    cnt2 += __popcll(__ballot(e == 2));
    cnt3 += __popcll(__ballot(e == 3));
  }
  int b0 = 0, b1 = cnt0, b2 = cnt0 + cnt1, b3 = cnt0 + cnt1 + cnt2;
  if (lane == 0) {
    offs[0] = 0; offs[1] = b1; offs[2] = b2; offs[3] = b3; offs[4] = b3 + cnt3;
  }
  unsigned long long below = (lane == 63) ? ~0ull >> 1 : ((1ull << lane) - 1);
  for (int c = 0; c < 32; ++c) {
    int e = myE[c];
    unsigned long long m0 = __ballot(e == 0), m1 = __ballot(e == 1);
    unsigned long long m2 = __ballot(e == 2), m3 = __ballot(e == 3);
    unsigned long long mm = (e == 0) ? m0 : (e == 1) ? m1 : (e == 2) ? m2 : m3;
    int base = (e == 0) ? b0 : (e == 1) ? b1 : (e == 2) ? b2 : b3;
    perm[base + __popcll(mm & below)] = c * 64 + lane;
    b0 += __popcll(m0); b1 += __popcll(m1); b2 += __popcll(m2); b3 += __popcll(m3);
  }
}

// ---------------------------------------------------------------- PE add
__global__ __launch_bounds__(256) void pe_add(const float* __restrict__ xin,
                                              float* __restrict__ x0) {
  int p = blockIdx.x * 256 + threadIdx.x;
  int t = p / 384;
  int jj = p - t * 384;
  int s = t & 255;
  float ang = (float)s * __expf((float)jj * -0.0239852613894f);
  float sn, cs;
  sincosf(ang, &sn, &cs);
  float2 xv = ((const float2*)xin)[p];
  float2 o;  o.x = xv.x + sn;  o.y = xv.y + cs;
  ((float2*)x0)[p] = o;
}

// ---------------------------------------------------------------- LayerNorm
__global__ __launch_bounds__(256) void ln_k(const float* __restrict__ x,
                                            const float* __restrict__ g,
                                            const float* __restrict__ bb,
                                            bf16_t* __restrict__ out) {
  int w = threadIdx.x >> 6, lane = threadIdx.x & 63;
  int t = blockIdx.x * 4 + w;
  const float4* xr = (const float4*)(x + (size_t)t * Hc);
  float4 v[3];
  float s = 0.f, s2 = 0.f;
  for (int i = 0; i < 3; ++i) {
    v[i] = xr[lane + i * 64];
    s  += v[i].x + v[i].y + v[i].z + v[i].w;
    s2 += v[i].x * v[i].x + v[i].y * v[i].y + v[i].z * v[i].z + v[i].w * v[i].w;
  }
  for (int o = 1; o < 64; o <<= 1) { s += __shfl_xor(s, o); s2 += __shfl_xor(s2, o); }
  float mu = s * (1.f / 768.f);
  float r = rsqrtf(s2 * (1.f / 768.f) - mu * mu + 1e-5f);
  bf16_t* orow = out + (size_t)t * Hc;
  for (int i = 0; i < 3; ++i) {
    int i4 = lane + i * 64;
    float4 gg = ((const float4*)g)[i4];
    float4 b4 = ((const float4*)bb)[i4];
    union { bf16_t h[4]; uint2 u; } pk;
    pk.h[0] = (bf16_t)((v[i].x - mu) * r * gg.x + b4.x);
    pk.h[1] = (bf16_t)((v[i].y - mu) * r * gg.y + b4.y);
    pk.h[2] = (bf16_t)((v[i].z - mu) * r * gg.z + b4.z);
    pk.h[3] = (bf16_t)((v[i].w - mu) * r * gg.w + b4.w);
    ((uint2*)orow)[i4] = pk.u;
  }
}

// ---------------------------------------------------------------- transpose+convert fp32 [K,N] -> bf16 [N,K]
// z decodes (l, m): l = z/mdiv, m = z%mdiv. src = sel(m)+l*sls (+m*sms if single src).
__global__ __launch_bounds__(256) void tconv(const float* __restrict__ s0,
                                             const float* __restrict__ s1,
                                             const float* __restrict__ s2,
                                             int mdiv, long sls, long sms,
                                             bf16_t* __restrict__ dst, long dls, long dms,
                                             int K, int N) {
  int z = blockIdx.z;
  int l = z / mdiv, m = z % mdiv;
  const float* src;
  if (s1) src = (m == 0 ? s0 : (m == 1 ? s1 : s2)) + (size_t)l * sls;
  else src = s0 + (size_t)l * sls + (size_t)m * sms;
  bf16_t* d = dst + (size_t)l * dls + (size_t)m * dms;
  int n0 = blockIdx.x * 64, k0 = blockIdx.y * 64;
  __shared__ float tl[64][65];
  int c = threadIdx.x & 63, r0 = threadIdx.x >> 6;
  for (int i = 0; i < 16; ++i) {
    int r = r0 + i * 4;
    tl[r][c] = src[(size_t)(k0 + r) * N + n0 + c];
  }
  __syncthreads();
  for (int i = 0; i < 16; ++i) {
    int r = r0 + i * 4;
    d[(size_t)(n0 + r) * K + k0 + c] = (bf16_t)tl[c][r];
  }
}

// ---------------------------------------------------------------- GEMM (global_load_lds staging)
// C[M,N] = A[M,K] * Bt[N,K]^T, BM=128 x BN tile, BK=32, 4 waves (2x2).
// MODE 0: QKV (out bf16 + range bias)
// MODE 1: FFN1 (gather rows via perm, GELU, grouped bf16 out)
// MODE 2: FFN2 split-K=2 -> fp32 partial buffers (plain stores, NO atomics)
template <int MODE, int BN>
__global__ __launch_bounds__(256) void gemm2(
    const bf16_t* __restrict__ A, const bf16_t* __restrict__ Bt,
    int K, int N, int kIters, long btStride, long biasStride,
    const int* __restrict__ perm, const int* __restrict__ offs,
    const float* __restrict__ bqp, const float* __restrict__ bkp,
    const float* __restrict__ bvp, const float* __restrict__ biasE,
    float* __restrict__ outF, bf16_t* __restrict__ outB) {
  constexpr int TN = BN / 32;       // acc tiles per wave in n
  constexpr int BCH = BN / 64;      // B gll16 per wave
  __shared__ bf16_t Ald[128 * 32];
  __shared__ bf16_t Bld[BN * 32];
  int tid = threadIdx.x, lane = tid & 63, w = tid >> 6;
  int quad = lane >> 4, col = lane & 15;
  int m0 = blockIdx.y * 128, n0 = blockIdx.x * BN;
  int e = 0, ks = 0, kStart = 0, off = 0, cnt = Tc;
  if (MODE == 1) e = blockIdx.z;
  if (MODE == 2) { e = blockIdx.z >> 1; ks = blockIdx.z & 1; kStart = ks * (K / 2); }
  if (MODE != 0) {
    off = offs[e];
    cnt = offs[e + 1] - off;
    if (m0 >= cnt) return;
  }
  const bf16_t* B0 = Bt + (size_t)e * btStride;

  // A staging: wave w covers rows 32w..32w+31 (2 gll16 of 16 rows)
  const bf16_t* ga[2];
  bf16_t* la[2];
  for (int j = 0; j < 2; ++j) {
    int rbase = 32 * w + 16 * j;
    int row = rbase + (lane >> 2);
    int ch = ((lane & 3) - (row >> 1)) & 3;
    int gm = m0 + row;
    int gmc = (gm < cnt) ? gm : (cnt - 1);
    int srow;
    if (MODE == 0) srow = gm;
    else if (MODE == 1) srow = perm[off + gmc];
    else srow = off + gmc;
    ga[j] = A + (size_t)srow * K + kStart + ch * 8;
    la[j] = Ald + rbase * 32;
  }
  // B staging
  const bf16_t* gb[BCH];
  bf16_t* lb[BCH];
  for (int j = 0; j < BCH; ++j) {
    int rbase = (BCH == 2) ? (32 * w + 16 * j) : (16 * w);
    int row = rbase + (lane >> 2);
    int ch = ((lane & 3) - (row >> 1)) & 3;
    gb[j] = B0 + (size_t)(n0 + row) * K + kStart + ch * 8;
    lb[j] = Bld + rbase * 32;
  }

  int wr = (w >> 1) * 64, wc = (w & 1) * (BN / 2);
  const bf16_t* ar[4];
  const bf16_t* br[TN];
  for (int r = 0; r < 4; ++r) {
    int row = wr + r * 16 + col;
    ar[r] = Ald + row * 32 + (((quad + (row >> 1)) & 3) << 3);
  }
  for (int c = 0; c < TN; ++c) {
    int row = wc + c * 16 + col;
    br[c] = Bld + row * 32 + (((quad + (row >> 1)) & 3) << 3);
  }

  const f32x4 z4 = {0.f, 0.f, 0.f, 0.f};
  f32x4 acc[4][TN];
  for (int r = 0; r < 4; ++r)
    for (int c = 0; c < TN; ++c) acc[r][c] = z4;

  for (int it = 0; it < kIters; ++it) {
    __syncthreads();
    gll16(ga[0], la[0]);
    gll16(ga[1], la[1]);
    for (int j = 0; j < BCH; ++j) gll16(gb[j], lb[j]);
    ga[0] += 32; ga[1] += 32;
    for (int j = 0; j < BCH; ++j) gb[j] += 32;
    __syncthreads();
    bf16x8 af[4], bv[TN];
    for (int r = 0; r < 4; ++r) af[r] = *(const bf16x8*)ar[r];
    for (int c = 0; c < TN; ++c) bv[c] = *(const bf16x8*)br[c];
    for (int r = 0; r < 4; ++r)
      for (int c = 0; c < TN; ++c)
        acc[r][c] = __builtin_amdgcn_mfma_f32_16x16x32_bf16(af[r], bv[c], acc[r][c], 0, 0, 0);
  }

  for (int r = 0; r < 4; ++r)
    for (int c = 0; c < TN; ++c) {
      int mloc = wr + r * 16 + quad * 4;
      int n = n0 + wc + c * 16 + col;
      for (int i = 0; i < 4; ++i) {
        int gm = m0 + mloc + i;
        float av = acc[r][c][i];
        if (MODE == 0) {
          float bias = (n < 768) ? bqp[n] : (n < 1536) ? bkp[n - 768] : bvp[n - 1536];
          outB[(size_t)gm * N + n] = (bf16_t)(av + bias);
        } else if (MODE == 1) {
          if (gm < cnt) {
            float v = av + biasE[(size_t)e * biasStride + n];
            float u = v * (0.7978845608f + 0.0356774081f * v * v);
            float t = 1.f - 2.f / (1.f + __expf(2.f * u));
            outB[(size_t)(off + gm) * N + n] = (bf16_t)(0.5f * v * (1.f + t));
          }
        } else {
          if (gm < cnt) {
            int tok = perm[off + gm];
            outF[(size_t)ks * Tc * Hc + (size_t)tok * N + n] = av;
          }
        }
      }
    }
}

// ---------------------------------------------------------------- attention
__global__ __launch_bounds__(256) void attn_k(const bf16_t* __restrict__ qkv,
                                              const int* __restrict__ np,
                                              float* __restrict__ x) {
  __shared__ bf16_t Kld[256 * 64];  // reused as P after scores
  __shared__ bf16_t Vt[64 * 256];   // V transposed [d][s], swizzled
  int tid = threadIdx.x, lane = tid & 63, w = tid >> 6;
  int qt = blockIdx.x;
  int b = blockIdx.y / NHc, h = blockIdx.y % NHc;

  for (int j = 0; j < 8; ++j) {
    int rbase = w * 64 + j * 8;
    int row = rbase + (lane >> 3);
    int oc = ((lane & 7) - row) & 7;
    const bf16_t* gp = qkv + ((size_t)(b * 256 + row)) * 2304 + 768 + h * 64 + oc * 8;
    gll16(gp, Kld + rbase * 64);
  }
  {
    int s = tid, shi = s >> 3, slo = s & 7;
    const uint4* vs = (const uint4*)(qkv + ((size_t)(b * 256 + s)) * 2304 + 1536 + h * 64);
    for (int cc = 0; cc < 8; ++cc) {
      uint4 pk = vs[cc];
      const bf16_t* pv = (const bf16_t*)&pk;
      for (int jj = 0; jj < 8; ++jj) {
        int d = cc * 8 + jj;
        Vt[d * 256 + ((shi + d) & 31) * 8 + slo] = pv[jj];
      }
    }
  }
  int quad = lane >> 4, col = lane & 15;
  float madd[16];
  for (int nt = 0; nt < 16; ++nt)
    madd[nt] = (np[b * 256 + nt * 16 + col] != 0) ? 0.f : -10000.f;
  int qrow = qt * 64 + w * 16 + col;
  const bf16_t* qb = qkv + ((size_t)(b * 256 + qrow)) * 2304 + h * 64;
  bf16x8 qf0 = *(const bf16x8*)(qb + quad * 8);
  bf16x8 qf1 = *(const bf16x8*)(qb + 32 + quad * 8);
  __syncthreads();

  const f32x4 z4 = {0.f, 0.f, 0.f, 0.f};
  f32x4 sc[16];
  for (int nt = 0; nt < 16; ++nt) {
    int row = nt * 16 + col;
    bf16x8 k0 = *(const bf16x8*)(Kld + row * 64 + (((0 + quad + row) & 7) << 3));
    bf16x8 k1 = *(const bf16x8*)(Kld + row * 64 + (((4 + quad + row) & 7) << 3));
    f32x4 z = z4;
    z = __builtin_amdgcn_mfma_f32_16x16x32_bf16(qf0, k0, z, 0, 0, 0);
    z = __builtin_amdgcn_mfma_f32_16x16x32_bf16(qf1, k1, z, 0, 0, 0);
    sc[nt] = z;
  }
  for (int nt = 0; nt < 16; ++nt) {
    float a = madd[nt];
    sc[nt][0] += a; sc[nt][1] += a; sc[nt][2] += a; sc[nt][3] += a;
  }
  float pm[4], rl[4];
  for (int i = 0; i < 4; ++i) {
    float m = -1e30f;
    for (int nt = 0; nt < 16; ++nt) m = fmaxf(m, sc[nt][i]);
    for (int o = 1; o < 16; o <<= 1) m = fmaxf(m, __shfl_xor(m, o));
    float ssum = 0.f;
    for (int nt = 0; nt < 16; ++nt) ssum += __expf(sc[nt][i] - m);
    for (int o = 1; o < 16; o <<= 1) ssum += __shfl_xor(ssum, o);
    pm[i] = m;
    rl[i] = 1.f / ssum;
  }
  __syncthreads();
  bf16_t* Pb = Kld + w * 4096;
  for (int nt = 0; nt < 16; ++nt)
    for (int i = 0; i < 4; ++i) {
      int prow = quad * 4 + i;
      int key = nt * 16 + col;
      Pb[prow * 256 + (((key >> 3) + prow) & 31) * 8 + (key & 7)] =
          (bf16_t)__expf(sc[nt][i] - pm[i]);
    }
  __syncthreads();
  f32x4 oacc[4];
  for (int i = 0; i < 4; ++i) oacc[i] = z4;
  for (int kk2 = 0; kk2 < 8; ++kk2) {
    bf16x8 pa = *(const bf16x8*)(Pb + col * 256 + (((kk2 * 4 + quad + col) & 31) << 3));
    for (int nt2 = 0; nt2 < 4; ++nt2) {
      int d = nt2 * 16 + col;
      bf16x8 bv8 = *(const bf16x8*)(Vt + d * 256 + (((kk2 * 4 + quad + d) & 31) << 3));
      oacc[nt2] = __builtin_amdgcn_mfma_f32_16x16x32_bf16(pa, bv8, oacc[nt2], 0, 0, 0);
    }
  }
  for (int nt2 = 0; nt2 < 4; ++nt2)
    for (int i = 0; i < 4; ++i) {
      size_t o = ((size_t)(b * 256 + qt * 64 + w * 16 + quad * 4 + i)) * Hc + h * 64 + nt2 * 16 + col;
      x[o] += oacc[nt2][i] * rl[i];
    }
}

// ---------------------------------------------------------------- combine partials + residual + b2 + permute
__global__ __launch_bounds__(256) void combine_k(const float* __restrict__ x0,
                                                 const float* __restrict__ pbuf,
                                                 const float* __restrict__ b2l,
                                                 const int* __restrict__ ntp,
                                                 const int* __restrict__ np,
                                                 float* __restrict__ dst) {
  int i = blockIdx.x * 256 + threadIdx.x;  // float4 index over 2048*192
  int t = i / 192, d = i - t * 192;
  int idx = np[t];
  float4 o;
  if (idx != 0) {
    int r = idx - 1;
    int e = ntp[r];
    size_t j = (size_t)r * 192 + d;
    float4 a = ((const float4*)x0)[j];
    float4 p0 = ((const float4*)pbuf)[j];
    float4 p1 = ((const float4*)pbuf)[(size_t)Tc * 192 + j];
    float4 bb = ((const float4*)(b2l + (size_t)e * Hc))[d];
    o.x = a.x + p0.x + p1.x + bb.x;
    o.y = a.y + p0.y + p1.y + bb.y;
    o.z = a.z + p0.z + p1.z + bb.z;
    o.w = a.w + p0.w + p1.w + bb.w;
  } else {
    o.x = o.y = o.z = o.w = 0.f;
  }
  ((float4*)dst)[i] = o;
}

// ---------------------------------------------------------------- host
extern "C" void kernel_launch(void* const* d_in, const int* in_sizes, int n_in,
                              void* d_out, int out_size, void* d_ws, size_t ws_size,
                              hipStream_t stream) {
  const float* x_in = (const float*)d_in[0];
  const int* note_pos = (const int*)d_in[1];
  const int* ntp = (const int*)d_in[2];
  const float* Wq = (const float*)d_in[3];
  const float* bq = (const float*)d_in[4];
  const float* Wk = (const float*)d_in[5];
  const float* bk = (const float*)d_in[6];
  const float* Wv = (const float*)d_in[7];
  const float* bv = (const float*)d_in[8];
  const float* ln1w = (const float*)d_in[9];
  const float* ln1b = (const float*)d_in[10];
  const float* ln2w = (const float*)d_in[11];
  const float* ln2b = (const float*)d_in[12];
  const float* W1 = (const float*)d_in[13];
  const float* b1 = (const float*)d_in[14];
  const float* W2 = (const float*)d_in[15];
  const float* b2 = (const float*)d_in[16];
  float* out = (float*)d_out;

  char* p = (char*)d_ws;
  auto carve = [&](size_t bytes) -> char* {
    char* r = p;
    p += (bytes + 255) & ~(size_t)255;
    return r;
  };
  float* xA = (float*)carve((size_t)Tc * Hc * 4);
  float* xB = (float*)carve((size_t)Tc * Hc * 4);
  float* pbuf = (float*)carve((size_t)2 * Tc * Hc * 4);
  bf16_t* h16 = (bf16_t*)carve((size_t)Tc * Hc * 2);
  bf16_t* big = (bf16_t*)carve((size_t)Tc * FFc * 2);  // union: qkv16 / act1
  bf16_t* qkv16 = big;
  bf16_t* act1 = big;
  bf16_t* wqkvt = (bf16_t*)carve((size_t)Lc * 2304 * 768 * 2);
  bf16_t* w1t = (bf16_t*)carve((size_t)Lc * NEc * FFc * Hc * 2);
  bf16_t* w2t = (bf16_t*)carve((size_t)Lc * NEc * Hc * FFc * 2);
  int* perm = (int*)carve(Tc * 4);
  int* offs = (int*)carve(64);

  route_k<<<1, 64, 0, stream>>>(ntp, perm, offs);
  pe_add<<<Tc * Hc / 2 / 256, 256, 0, stream>>>(x_in, xA);

  // All weight transposes up front (weights are layer-loop invariant).
  tconv<<<dim3(12, 12, 6), 256, 0, stream>>>(Wq, Wk, Wv, 3, (long)Hc * Hc, 0L,
                                             wqkvt, (long)2304 * 768, (long)Hc * Hc, Hc, Hc);
  tconv<<<dim3(48, 12, 8), 256, 0, stream>>>(W1, nullptr, nullptr, 4,
                                             (long)NEc * Hc * FFc, (long)Hc * FFc,
                                             w1t, (long)NEc * FFc * Hc, (long)FFc * Hc, Hc, FFc);
  tconv<<<dim3(12, 48, 8), 256, 0, stream>>>(W2, nullptr, nullptr, 4,
                                             (long)NEc * FFc * Hc, (long)FFc * Hc,
                                             w2t, (long)NEc * Hc * FFc, (long)Hc * FFc, FFc, Hc);

  float* xcur = xA;
  for (int l = 0; l < Lc; ++l) {
    float* xdst = (l == Lc - 1) ? out : xB;
    ln_k<<<Tc / 4, 256, 0, stream>>>(xcur, ln1w + l * Hc, ln1b + l * Hc, h16);
    gemm2<0, 64><<<dim3(36, 16, 1), 256, 0, stream>>>(
        h16, wqkvt + (size_t)l * 2304 * 768, Hc, 2304, 24, 0L, 0L, perm, offs,
        bq + l * Hc, bk + l * Hc, bv + l * Hc, nullptr, nullptr, qkv16);
    attn_k<<<dim3(4, Bc * NHc), 256, 0, stream>>>(qkv16, note_pos, xcur);
    ln_k<<<Tc / 4, 256, 0, stream>>>(xcur, ln2w + l * Hc, ln2b + l * Hc, h16);
    gemm2<1, 64><<<dim3(48, 16, NEc), 256, 0, stream>>>(
        h16, w1t + (size_t)l * NEc * FFc * Hc, Hc, FFc, 24, (long)FFc * Hc, (long)FFc,
        perm, offs, nullptr, nullptr, nullptr, b1 + (size_t)l * NEc * FFc, nullptr, act1);
    gemm2<2, 64><<<dim3(12, 16, NEc * 2), 256, 0, stream>>>(
        act1, w2t + (size_t)l * NEc * Hc * FFc, FFc, Hc, 48, (long)Hc * FFc, 0L,
        perm, offs, nullptr, nullptr, nullptr, nullptr, pbuf, nullptr);
    combine_k<<<Tc * 192 / 256, 256, 0, stream>>>(xcur, pbuf, b2 + (size_t)l * NEc * Hc,
                                                  ntp, note_pos, xdst);
    float* tmp = xcur; xcur = xdst; xB = tmp;  // ping-pong (xB holds the free buffer)
  }
}

// Round 4
// 454.603 us; speedup vs baseline: 1.8534x; 1.0701x over previous
//
#include <hip/hip_runtime.h>

typedef __bf16 bf16_t;
typedef __attribute__((ext_vector_type(8))) __bf16 bf16x8;
typedef __attribute__((ext_vector_type(4))) float f32x4;

static constexpr int Lc = 2, NEc = 4, Hc = 768, FFc = 3072, NHc = 12;
static constexpr int Bc = 8, Tc = 2048;

__device__ __forceinline__ void gll16(const bf16_t* g, bf16_t* l) {
  __builtin_amdgcn_global_load_lds(
      (const __attribute__((address_space(1))) void*)g,
      (__attribute__((address_space(3))) void*)l, 16, 0, 0);
}

// ---------------------------------------------------------------- route (1 wave, ballot counting sort)
__global__ __launch_bounds__(64) void route_k(const int* __restrict__ ntp,
                                              int* __restrict__ perm,
                                              int* __restrict__ offs) {
  int lane = threadIdx.x;
  int myE[32];
  int cnt0 = 0, cnt1 = 0, cnt2 = 0, cnt3 = 0;
  for (int c = 0; c < 32; ++c) {
    int e = ntp[c * 64 + lane];
    myE[c] = e;
    cnt0 += __popcll(__ballot(e == 0));
    cnt1 += __popcll(__ballot(e == 1));
    cnt2 += __popcll(__ballot(e == 2));
    cnt3 += __popcll(__ballot(e == 3));
  }
  int b0 = 0, b1 = cnt0, b2 = cnt0 + cnt1, b3 = cnt0 + cnt1 + cnt2;
  if (lane == 0) {
    offs[0] = 0; offs[1] = b1; offs[2] = b2; offs[3] = b3; offs[4] = b3 + cnt3;
  }
  unsigned long long below = (lane == 63) ? ~0ull >> 1 : ((1ull << lane) - 1);
  for (int c = 0; c < 32; ++c) {
    int e = myE[c];
    unsigned long long m0 = __ballot(e == 0), m1 = __ballot(e == 1);
    unsigned long long m2 = __ballot(e == 2), m3 = __ballot(e == 3);
    unsigned long long mm = (e == 0) ? m0 : (e == 1) ? m1 : (e == 2) ? m2 : m3;
    int base = (e == 0) ? b0 : (e == 1) ? b1 : (e == 2) ? b2 : b3;
    perm[base + __popcll(mm & below)] = c * 64 + lane;
    b0 += __popcll(m0); b1 += __popcll(m1); b2 += __popcll(m2); b3 += __popcll(m3);
  }
}

// ---------------------------------------------------------------- PE add
__global__ __launch_bounds__(256) void pe_add(const float* __restrict__ xin,
                                              float* __restrict__ x0) {
  int p = blockIdx.x * 256 + threadIdx.x;
  int t = p / 384;
  int jj = p - t * 384;
  int s = t & 255;
  float ang = (float)s * __expf((float)jj * -0.0239852613894f);
  float sn, cs;
  sincosf(ang, &sn, &cs);
  float2 xv = ((const float2*)xin)[p];
  float2 o;  o.x = xv.x + sn;  o.y = xv.y + cs;
  ((float2*)x0)[p] = o;
}

// ---------------------------------------------------------------- LayerNorm
__global__ __launch_bounds__(256) void ln_k(const float* __restrict__ x,
                                            const float* __restrict__ g,
                                            const float* __restrict__ bb,
                                            bf16_t* __restrict__ out) {
  int w = threadIdx.x >> 6, lane = threadIdx.x & 63;
  int t = blockIdx.x * 4 + w;
  const float4* xr = (const float4*)(x + (size_t)t * Hc);
  float4 v[3];
  float s = 0.f, s2 = 0.f;
  for (int i = 0; i < 3; ++i) {
    v[i] = xr[lane + i * 64];
    s  += v[i].x + v[i].y + v[i].z + v[i].w;
    s2 += v[i].x * v[i].x + v[i].y * v[i].y + v[i].z * v[i].z + v[i].w * v[i].w;
  }
  for (int o = 1; o < 64; o <<= 1) { s += __shfl_xor(s, o); s2 += __shfl_xor(s2, o); }
  float mu = s * (1.f / 768.f);
  float r = rsqrtf(s2 * (1.f / 768.f) - mu * mu + 1e-5f);
  bf16_t* orow = out + (size_t)t * Hc;
  for (int i = 0; i < 3; ++i) {
    int i4 = lane + i * 64;
    float4 gg = ((const float4*)g)[i4];
    float4 b4 = ((const float4*)bb)[i4];
    union { bf16_t h[4]; uint2 u; } pk;
    pk.h[0] = (bf16_t)((v[i].x - mu) * r * gg.x + b4.x);
    pk.h[1] = (bf16_t)((v[i].y - mu) * r * gg.y + b4.y);
    pk.h[2] = (bf16_t)((v[i].z - mu) * r * gg.z + b4.z);
    pk.h[3] = (bf16_t)((v[i].w - mu) * r * gg.w + b4.w);
    ((uint2*)orow)[i4] = pk.u;
  }
}

// ---------------------------------------------------------------- transpose+convert fp32 [K,N] -> bf16 [N,K]
__global__ __launch_bounds__(256) void tconv(const float* __restrict__ s0,
                                             const float* __restrict__ s1,
                                             const float* __restrict__ s2,
                                             int mdiv, long sls, long sms,
                                             bf16_t* __restrict__ dst, long dls, long dms,
                                             int K, int N) {
  int z = blockIdx.z;
  int l = z / mdiv, m = z % mdiv;
  const float* src;
  if (s1) src = (m == 0 ? s0 : (m == 1 ? s1 : s2)) + (size_t)l * sls;
  else src = s0 + (size_t)l * sls + (size_t)m * sms;
  bf16_t* d = dst + (size_t)l * dls + (size_t)m * dms;
  int n0 = blockIdx.x * 64, k0 = blockIdx.y * 64;
  __shared__ float tl[64][65];
  int c = threadIdx.x & 63, r0 = threadIdx.x >> 6;
  for (int i = 0; i < 16; ++i) {
    int r = r0 + i * 4;
    tl[r][c] = src[(size_t)(k0 + r) * N + n0 + c];
  }
  __syncthreads();
  for (int i = 0; i < 16; ++i) {
    int r = r0 + i * 4;
    d[(size_t)(n0 + r) * K + k0 + c] = (bf16_t)tl[c][r];
  }
}

// ---------------------------------------------------------------- GEMM, BK=64, BN=64, BM template
// LDS rows hold 64 bf16 (8 chunks of 8) with rotation swizzle: slot s of row r = global chunk (s-r)&7.
// MODE 0: QKV (out bf16 + range bias)  MODE 1: FFN1 (gather via perm, GELU, grouped out)
// MODE 2: FFN2 split-K=2 -> fp32 partial buffers
template <int MODE, int BM>
__global__ __launch_bounds__(256) void gemm2(
    const bf16_t* __restrict__ A, const bf16_t* __restrict__ Bt,
    int K, int N, int kIters, long btStride, long biasStride,
    const int* __restrict__ perm, const int* __restrict__ offs,
    const float* __restrict__ bqp, const float* __restrict__ bkp,
    const float* __restrict__ bvp, const float* __restrict__ biasE,
    float* __restrict__ outF, bf16_t* __restrict__ outB) {
  constexpr int TM = BM / 32;   // 4 (BM=128) or 2 (BM=64)
  constexpr int TN = 2;
  constexpr int AI = BM / 32;   // A-staging instrs per wave
  __shared__ bf16_t Ald[BM * 64];
  __shared__ bf16_t Bld[64 * 64];
  int tid = threadIdx.x, lane = tid & 63, w = tid >> 6;
  int quad = lane >> 4, col = lane & 15;
  int m0 = blockIdx.y * BM, n0 = blockIdx.x * 64;
  int e = 0, ks = 0, kStart = 0, off = 0, cnt = Tc;
  if (MODE == 1) e = blockIdx.z;
  if (MODE == 2) { e = blockIdx.z >> 1; ks = blockIdx.z & 1; kStart = ks * (K / 2); }
  if (MODE != 0) {
    off = offs[e];
    cnt = offs[e + 1] - off;
    if (m0 >= cnt) return;
  }
  const bf16_t* B0 = Bt + (size_t)e * btStride;

  // A staging: wave w covers rows [w*BM/4, w*BM/4 + BM/4), 8 rows per gll16
  const bf16_t* ga[AI];
  bf16_t* la[AI];
  for (int j = 0; j < AI; ++j) {
    int rbase = w * (BM / 4) + j * 8;
    int row = rbase + (lane >> 3);
    int ch = ((lane & 7) - row) & 7;
    int gm = m0 + row;
    int gmc = (gm < cnt) ? gm : (cnt - 1);
    int srow;
    if (MODE == 0) srow = gm;
    else if (MODE == 1) srow = perm[off + gmc];
    else srow = off + gmc;
    ga[j] = A + (size_t)srow * K + kStart + ch * 8;
    la[j] = Ald + rbase * 64;
  }
  // B staging: 64 rows, wave w covers [w*16, w*16+16)
  const bf16_t* gb[2];
  bf16_t* lb[2];
  for (int j = 0; j < 2; ++j) {
    int rbase = w * 16 + j * 8;
    int row = rbase + (lane >> 3);
    int ch = ((lane & 7) - row) & 7;
    gb[j] = B0 + (size_t)(n0 + row) * K + kStart + ch * 8;
    lb[j] = Bld + rbase * 64;
  }

  int wr = (w >> 1) * (BM / 2), wc = (w & 1) * 32;
  int aoff[TM], boff[TN];
  for (int r = 0; r < TM; ++r) {
    int row = wr + r * 16 + col;
    aoff[r] = row * 64 + (((quad + row) & 7) << 3);
  }
  for (int c = 0; c < TN; ++c) {
    int row = wc + c * 16 + col;
    boff[c] = row * 64 + (((quad + row) & 7) << 3);
  }

  const f32x4 z4 = {0.f, 0.f, 0.f, 0.f};
  f32x4 acc[TM][TN];
  for (int r = 0; r < TM; ++r)
    for (int c = 0; c < TN; ++c) acc[r][c] = z4;

  for (int it = 0; it < kIters; ++it) {
    __syncthreads();
    for (int j = 0; j < AI; ++j) gll16(ga[j], la[j]);
    for (int j = 0; j < 2; ++j) gll16(gb[j], lb[j]);
    for (int j = 0; j < AI; ++j) ga[j] += 64;
    for (int j = 0; j < 2; ++j) gb[j] += 64;
    __syncthreads();
    for (int kk = 0; kk < 2; ++kk) {
      bf16x8 af[TM], bv[TN];
      for (int r = 0; r < TM; ++r) af[r] = *(const bf16x8*)(Ald + (aoff[r] ^ (kk << 5)));
      for (int c = 0; c < TN; ++c) bv[c] = *(const bf16x8*)(Bld + (boff[c] ^ (kk << 5)));
      for (int r = 0; r < TM; ++r)
        for (int c = 0; c < TN; ++c)
          acc[r][c] = __builtin_amdgcn_mfma_f32_16x16x32_bf16(af[r], bv[c], acc[r][c], 0, 0, 0);
    }
  }

  for (int r = 0; r < TM; ++r)
    for (int c = 0; c < TN; ++c) {
      int mloc = wr + r * 16 + quad * 4;
      int n = n0 + wc + c * 16 + col;
      for (int i = 0; i < 4; ++i) {
        int gm = m0 + mloc + i;
        float av = acc[r][c][i];
        if (MODE == 0) {
          float bias = (n < 768) ? bqp[n] : (n < 1536) ? bkp[n - 768] : bvp[n - 1536];
          outB[(size_t)gm * N + n] = (bf16_t)(av + bias);
        } else if (MODE == 1) {
          if (gm < cnt) {
            float v = av + biasE[(size_t)e * biasStride + n];
            float u = v * (0.7978845608f + 0.0356774081f * v * v);
            float t = 1.f - 2.f / (1.f + __expf(2.f * u));
            outB[(size_t)(off + gm) * N + n] = (bf16_t)(0.5f * v * (1.f + t));
          }
        } else {
          if (gm < cnt) {
            int tok = perm[off + gm];
            outF[(size_t)ks * Tc * Hc + (size_t)tok * N + n] = av;
          }
        }
      }
    }
}

// ---------------------------------------------------------------- attention
__global__ __launch_bounds__(256) void attn_k(const bf16_t* __restrict__ qkv,
                                              const int* __restrict__ np,
                                              float* __restrict__ x) {
  __shared__ bf16_t Kld[256 * 64];  // reused as P after scores
  __shared__ bf16_t Vt[64 * 256];   // V transposed [d][s], swizzled
  int tid = threadIdx.x, lane = tid & 63, w = tid >> 6;
  int qt = blockIdx.x;
  int b = blockIdx.y / NHc, h = blockIdx.y % NHc;

  for (int j = 0; j < 8; ++j) {
    int rbase = w * 64 + j * 8;
    int row = rbase + (lane >> 3);
    int oc = ((lane & 7) - row) & 7;
    const bf16_t* gp = qkv + ((size_t)(b * 256 + row)) * 2304 + 768 + h * 64 + oc * 8;
    gll16(gp, Kld + rbase * 64);
  }
  {
    int s = tid, shi = s >> 3, slo = s & 7;
    const uint4* vs = (const uint4*)(qkv + ((size_t)(b * 256 + s)) * 2304 + 1536 + h * 64);
    for (int cc = 0; cc < 8; ++cc) {
      uint4 pk = vs[cc];
      const bf16_t* pv = (const bf16_t*)&pk;
      for (int jj = 0; jj < 8; ++jj) {
        int d = cc * 8 + jj;
        Vt[d * 256 + ((shi + d) & 31) * 8 + slo] = pv[jj];
      }
    }
  }
  int quad = lane >> 4, col = lane & 15;
  float madd[16];
  for (int nt = 0; nt < 16; ++nt)
    madd[nt] = (np[b * 256 + nt * 16 + col] != 0) ? 0.f : -10000.f;
  int qrow = qt * 64 + w * 16 + col;
  const bf16_t* qb = qkv + ((size_t)(b * 256 + qrow)) * 2304 + h * 64;
  bf16x8 qf0 = *(const bf16x8*)(qb + quad * 8);
  bf16x8 qf1 = *(const bf16x8*)(qb + 32 + quad * 8);
  __syncthreads();

  const f32x4 z4 = {0.f, 0.f, 0.f, 0.f};
  f32x4 sc[16];
  for (int nt = 0; nt < 16; ++nt) {
    int row = nt * 16 + col;
    bf16x8 k0 = *(const bf16x8*)(Kld + row * 64 + (((0 + quad + row) & 7) << 3));
    bf16x8 k1 = *(const bf16x8*)(Kld + row * 64 + (((4 + quad + row) & 7) << 3));
    f32x4 z = z4;
    z = __builtin_amdgcn_mfma_f32_16x16x32_bf16(qf0, k0, z, 0, 0, 0);
    z = __builtin_amdgcn_mfma_f32_16x16x32_bf16(qf1, k1, z, 0, 0, 0);
    sc[nt] = z;
  }
  for (int nt = 0; nt < 16; ++nt) {
    float a = madd[nt];
    sc[nt][0] += a; sc[nt][1] += a; sc[nt][2] += a; sc[nt][3] += a;
  }
  float pm[4], rl[4];
  for (int i = 0; i < 4; ++i) {
    float m = -1e30f;
    for (int nt = 0; nt < 16; ++nt) m = fmaxf(m, sc[nt][i]);
    for (int o = 1; o < 16; o <<= 1) m = fmaxf(m, __shfl_xor(m, o));
    float ssum = 0.f;
    for (int nt = 0; nt < 16; ++nt) ssum += __expf(sc[nt][i] - m);
    for (int o = 1; o < 16; o <<= 1) ssum += __shfl_xor(ssum, o);
    pm[i] = m;
    rl[i] = 1.f / ssum;
  }
  __syncthreads();
  bf16_t* Pb = Kld + w * 4096;
  for (int nt = 0; nt < 16; ++nt)
    for (int i = 0; i < 4; ++i) {
      int prow = quad * 4 + i;
      int key = nt * 16 + col;
      Pb[prow * 256 + (((key >> 3) + prow) & 31) * 8 + (key & 7)] =
          (bf16_t)__expf(sc[nt][i] - pm[i]);
    }
  __syncthreads();
  f32x4 oacc[4];
  for (int i = 0; i < 4; ++i) oacc[i] = z4;
  for (int kk2 = 0; kk2 < 8; ++kk2) {
    bf16x8 pa = *(const bf16x8*)(Pb + col * 256 + (((kk2 * 4 + quad + col) & 31) << 3));
    for (int nt2 = 0; nt2 < 4; ++nt2) {
      int d = nt2 * 16 + col;
      bf16x8 bv8 = *(const bf16x8*)(Vt + d * 256 + (((kk2 * 4 + quad + d) & 31) << 3));
      oacc[nt2] = __builtin_amdgcn_mfma_f32_16x16x32_bf16(pa, bv8, oacc[nt2], 0, 0, 0);
    }
  }
  for (int nt2 = 0; nt2 < 4; ++nt2)
    for (int i = 0; i < 4; ++i) {
      size_t o = ((size_t)(b * 256 + qt * 64 + w * 16 + quad * 4 + i)) * Hc + h * 64 + nt2 * 16 + col;
      x[o] += oacc[nt2][i] * rl[i];
    }
}

// ---------------------------------------------------------------- combine partials + residual + b2 + permute
__global__ __launch_bounds__(256) void combine_k(const float* __restrict__ x0,
                                                 const float* __restrict__ pbuf,
                                                 const float* __restrict__ b2l,
                                                 const int* __restrict__ ntp,
                                                 const int* __restrict__ np,
                                                 float* __restrict__ dst) {
  int i = blockIdx.x * 256 + threadIdx.x;  // float4 index over 2048*192
  int t = i / 192, d = i - t * 192;
  int idx = np[t];
  float4 o;
  if (idx != 0) {
    int r = idx - 1;
    int e = ntp[r];
    size_t j = (size_t)r * 192 + d;
    float4 a = ((const float4*)x0)[j];
    float4 p0 = ((const float4*)pbuf)[j];
    float4 p1 = ((const float4*)pbuf)[(size_t)Tc * 192 + j];
    float4 bb = ((const float4*)(b2l + (size_t)e * Hc))[d];
    o.x = a.x + p0.x + p1.x + bb.x;
    o.y = a.y + p0.y + p1.y + bb.y;
    o.z = a.z + p0.z + p1.z + bb.z;
    o.w = a.w + p0.w + p1.w + bb.w;
  } else {
    o.x = o.y = o.z = o.w = 0.f;
  }
  ((float4*)dst)[i] = o;
}

// ---------------------------------------------------------------- host
extern "C" void kernel_launch(void* const* d_in, const int* in_sizes, int n_in,
                              void* d_out, int out_size, void* d_ws, size_t ws_size,
                              hipStream_t stream) {
  const float* x_in = (const float*)d_in[0];
  const int* note_pos = (const int*)d_in[1];
  const int* ntp = (const int*)d_in[2];
  const float* Wq = (const float*)d_in[3];
  const float* bq = (const float*)d_in[4];
  const float* Wk = (const float*)d_in[5];
  const float* bk = (const float*)d_in[6];
  const float* Wv = (const float*)d_in[7];
  const float* bv = (const float*)d_in[8];
  const float* ln1w = (const float*)d_in[9];
  const float* ln1b = (const float*)d_in[10];
  const float* ln2w = (const float*)d_in[11];
  const float* ln2b = (const float*)d_in[12];
  const float* W1 = (const float*)d_in[13];
  const float* b1 = (const float*)d_in[14];
  const float* W2 = (const float*)d_in[15];
  const float* b2 = (const float*)d_in[16];
  float* out = (float*)d_out;

  char* p = (char*)d_ws;
  auto carve = [&](size_t bytes) -> char* {
    char* r = p;
    p += (bytes + 255) & ~(size_t)255;
    return r;
  };
  float* xA = (float*)carve((size_t)Tc * Hc * 4);
  float* xB = (float*)carve((size_t)Tc * Hc * 4);
  float* pbuf = (float*)carve((size_t)2 * Tc * Hc * 4);
  bf16_t* h16 = (bf16_t*)carve((size_t)Tc * Hc * 2);
  bf16_t* big = (bf16_t*)carve((size_t)Tc * FFc * 2);  // union: qkv16 / act1
  bf16_t* qkv16 = big;
  bf16_t* act1 = big;
  bf16_t* wqkvt = (bf16_t*)carve((size_t)Lc * 2304 * 768 * 2);
  bf16_t* w1t = (bf16_t*)carve((size_t)Lc * NEc * FFc * Hc * 2);
  bf16_t* w2t = (bf16_t*)carve((size_t)Lc * NEc * Hc * FFc * 2);
  int* perm = (int*)carve(Tc * 4);
  int* offs = (int*)carve(64);

  route_k<<<1, 64, 0, stream>>>(ntp, perm, offs);
  pe_add<<<Tc * Hc / 2 / 256, 256, 0, stream>>>(x_in, xA);

  // All weight transposes up front (layer-loop invariant).
  tconv<<<dim3(12, 12, 6), 256, 0, stream>>>(Wq, Wk, Wv, 3, (long)Hc * Hc, 0L,
                                             wqkvt, (long)2304 * 768, (long)Hc * Hc, Hc, Hc);
  tconv<<<dim3(48, 12, 8), 256, 0, stream>>>(W1, nullptr, nullptr, 4,
                                             (long)NEc * Hc * FFc, (long)Hc * FFc,
                                             w1t, (long)NEc * FFc * Hc, (long)FFc * Hc, Hc, FFc);
  tconv<<<dim3(12, 48, 8), 256, 0, stream>>>(W2, nullptr, nullptr, 4,
                                             (long)NEc * FFc * Hc, (long)FFc * Hc,
                                             w2t, (long)NEc * Hc * FFc, (long)Hc * FFc, FFc, Hc);

  float* xcur = xA;
  for (int l = 0; l < Lc; ++l) {
    float* xdst = (l == Lc - 1) ? out : xB;
    ln_k<<<Tc / 4, 256, 0, stream>>>(xcur, ln1w + l * Hc, ln1b + l * Hc, h16);
    gemm2<0, 128><<<dim3(36, 16, 1), 256, 0, stream>>>(
        h16, wqkvt + (size_t)l * 2304 * 768, Hc, 2304, 12, 0L, 0L, perm, offs,
        bq + l * Hc, bk + l * Hc, bv + l * Hc, nullptr, nullptr, qkv16);
    attn_k<<<dim3(4, Bc * NHc), 256, 0, stream>>>(qkv16, note_pos, xcur);
    ln_k<<<Tc / 4, 256, 0, stream>>>(xcur, ln2w + l * Hc, ln2b + l * Hc, h16);
    gemm2<1, 128><<<dim3(48, 16, NEc), 256, 0, stream>>>(
        h16, w1t + (size_t)l * NEc * FFc * Hc, Hc, FFc, 12, (long)FFc * Hc, (long)FFc,
        perm, offs, nullptr, nullptr, nullptr, b1 + (size_t)l * NEc * FFc, nullptr, act1);
    gemm2<2, 64><<<dim3(12, 32, NEc * 2), 256, 0, stream>>>(
        act1, w2t + (size_t)l * NEc * Hc * FFc, FFc, Hc, 24, (long)Hc * FFc, 0L,
        perm, offs, nullptr, nullptr, nullptr, nullptr, pbuf, nullptr);
    combine_k<<<Tc * 192 / 256, 256, 0, stream>>>(xcur, pbuf, b2 + (size_t)l * NEc * Hc,
                                                  ntp, note_pos, xdst);
    float* tmp = xcur; xcur = xdst; xB = tmp;  // ping-pong
  }
}

// Round 5
// 447.677 us; speedup vs baseline: 1.8820x; 1.0155x over previous
//
#include <hip/hip_runtime.h>

typedef __bf16 bf16_t;
typedef __attribute__((ext_vector_type(8))) __bf16 bf16x8;
typedef __attribute__((ext_vector_type(4))) float f32x4;

static constexpr int Lc = 2, NEc = 4, Hc = 768, FFc = 3072, NHc = 12;
static constexpr int Bc = 8, Tc = 2048;

__device__ __forceinline__ void gll16(const bf16_t* g, bf16_t* l) {
  __builtin_amdgcn_global_load_lds(
      (const __attribute__((address_space(1))) void*)g,
      (__attribute__((address_space(3))) void*)l, 16, 0, 0);
}

// ---------------------------------------------------------------- prep: block 0 = route (wave 0), blocks 1.. = PE add
__global__ __launch_bounds__(256) void prep_k(const float* __restrict__ xin,
                                              const int* __restrict__ ntp,
                                              float* __restrict__ x0,
                                              int* __restrict__ perm,
                                              int* __restrict__ offs) {
  if (blockIdx.x == 0) {
    int tid = threadIdx.x;
    if (tid >= 64) return;
    int lane = tid;
    int myE[32];
    int cnt0 = 0, cnt1 = 0, cnt2 = 0, cnt3 = 0;
    for (int c = 0; c < 32; ++c) {
      int e = ntp[c * 64 + lane];
      myE[c] = e;
      cnt0 += __popcll(__ballot(e == 0));
      cnt1 += __popcll(__ballot(e == 1));
      cnt2 += __popcll(__ballot(e == 2));
      cnt3 += __popcll(__ballot(e == 3));
    }
    int b0 = 0, b1 = cnt0, b2 = cnt0 + cnt1, b3 = cnt0 + cnt1 + cnt2;
    if (lane == 0) {
      offs[0] = 0; offs[1] = b1; offs[2] = b2; offs[3] = b3; offs[4] = b3 + cnt3;
    }
    unsigned long long below = (lane == 63) ? ~0ull >> 1 : ((1ull << lane) - 1);
    for (int c = 0; c < 32; ++c) {
      int e = myE[c];
      unsigned long long m0 = __ballot(e == 0), m1 = __ballot(e == 1);
      unsigned long long m2 = __ballot(e == 2), m3 = __ballot(e == 3);
      unsigned long long mm = (e == 0) ? m0 : (e == 1) ? m1 : (e == 2) ? m2 : m3;
      int base = (e == 0) ? b0 : (e == 1) ? b1 : (e == 2) ? b2 : b3;
      perm[base + __popcll(mm & below)] = c * 64 + lane;
      b0 += __popcll(m0); b1 += __popcll(m1); b2 += __popcll(m2); b3 += __popcll(m3);
    }
    return;
  }
  int p = (blockIdx.x - 1) * 256 + threadIdx.x;  // pair index over T*H/2
  int t = p / 384;
  int jj = p - t * 384;
  int s = t & 255;
  float ang = (float)s * __expf((float)jj * -0.0239852613894f);
  float sn, cs;
  sincosf(ang, &sn, &cs);
  float2 xv = ((const float2*)xin)[p];
  float2 o;  o.x = xv.x + sn;  o.y = xv.y + cs;
  ((float2*)x0)[p] = o;
}

// ---------------------------------------------------------------- LayerNorm
__global__ __launch_bounds__(256) void ln_k(const float* __restrict__ x,
                                            const float* __restrict__ g,
                                            const float* __restrict__ bb,
                                            bf16_t* __restrict__ out) {
  int w = threadIdx.x >> 6, lane = threadIdx.x & 63;
  int t = blockIdx.x * 4 + w;
  const float4* xr = (const float4*)(x + (size_t)t * Hc);
  float4 v[3];
  float s = 0.f, s2 = 0.f;
  for (int i = 0; i < 3; ++i) {
    v[i] = xr[lane + i * 64];
    s  += v[i].x + v[i].y + v[i].z + v[i].w;
    s2 += v[i].x * v[i].x + v[i].y * v[i].y + v[i].z * v[i].z + v[i].w * v[i].w;
  }
  for (int o = 1; o < 64; o <<= 1) { s += __shfl_xor(s, o); s2 += __shfl_xor(s2, o); }
  float mu = s * (1.f / 768.f);
  float r = rsqrtf(s2 * (1.f / 768.f) - mu * mu + 1e-5f);
  bf16_t* orow = out + (size_t)t * Hc;
  for (int i = 0; i < 3; ++i) {
    int i4 = lane + i * 64;
    float4 gg = ((const float4*)g)[i4];
    float4 b4 = ((const float4*)bb)[i4];
    union { bf16_t h[4]; uint2 u; } pk;
    pk.h[0] = (bf16_t)((v[i].x - mu) * r * gg.x + b4.x);
    pk.h[1] = (bf16_t)((v[i].y - mu) * r * gg.y + b4.y);
    pk.h[2] = (bf16_t)((v[i].z - mu) * r * gg.z + b4.z);
    pk.h[3] = (bf16_t)((v[i].w - mu) * r * gg.w + b4.w);
    ((uint2*)orow)[i4] = pk.u;
  }
}

// ---------------------------------------------------------------- unified transpose+convert fp32 [K,N] -> bf16 [N,K]
// Linear grid over all weight tiles: QKV (864) | W1 (4608) | W2 (4608).
__global__ __launch_bounds__(256) void tconv_all(const float* __restrict__ Wq,
                                                 const float* __restrict__ Wk,
                                                 const float* __restrict__ Wv,
                                                 const float* __restrict__ W1,
                                                 const float* __restrict__ W2,
                                                 bf16_t* __restrict__ wqkvt,
                                                 bf16_t* __restrict__ w1t,
                                                 bf16_t* __restrict__ w2t) {
  int t = blockIdx.x;
  const float* src;
  bf16_t* d;
  int K, N, n0, k0;
  if (t < 864) {
    int z = t / 144, r = t % 144;
    int l = z / 3, m = z % 3;
    src = (m == 0 ? Wq : (m == 1 ? Wk : Wv)) + (size_t)l * Hc * Hc;
    d = wqkvt + (size_t)l * 2304 * 768 + (size_t)m * Hc * Hc;
    K = 768; N = 768;
    n0 = (r % 12) * 64; k0 = (r / 12) * 64;
  } else if (t < 864 + 4608) {
    t -= 864;
    int z = t / 576, r = t % 576;
    src = W1 + (size_t)z * Hc * FFc;
    d = w1t + (size_t)z * FFc * Hc;
    K = 768; N = 3072;
    n0 = (r % 48) * 64; k0 = (r / 48) * 64;
  } else {
    t -= 864 + 4608;
    int z = t / 576, r = t % 576;
    src = W2 + (size_t)z * FFc * Hc;
    d = w2t + (size_t)z * Hc * FFc;
    K = 3072; N = 768;
    n0 = (r % 12) * 64; k0 = (r / 12) * 64;
  }
  __shared__ float tl[64][65];
  int c = threadIdx.x & 63, r0 = threadIdx.x >> 6;
  for (int i = 0; i < 16; ++i) {
    int r = r0 + i * 4;
    tl[r][c] = src[(size_t)(k0 + r) * N + n0 + c];
  }
  __syncthreads();
  for (int i = 0; i < 16; ++i) {
    int r = r0 + i * 4;
    d[(size_t)(n0 + r) * K + k0 + c] = (bf16_t)tl[c][r];
  }
}

// ---------------------------------------------------------------- GEMM, BM=64, BN=64, BK=64, 4 waves (2x2)
// LDS rows: 64 bf16 (8 chunks of 8), rotation swizzle: slot s of row r holds global chunk (s-r)&7.
// MODE 0: QKV (out bf16 + range bias)  MODE 1: FFN1 (gather via perm, GELU, grouped out)
// MODE 2: FFN2 split-K=2 -> fp32 partial buffers
template <int MODE>
__global__ __launch_bounds__(256) void gemm2(
    const bf16_t* __restrict__ A, const bf16_t* __restrict__ Bt,
    int K, int N, int kIters, long btStride, long biasStride,
    const int* __restrict__ perm, const int* __restrict__ offs,
    const float* __restrict__ bqp, const float* __restrict__ bkp,
    const float* __restrict__ bvp, const float* __restrict__ biasE,
    float* __restrict__ outF, bf16_t* __restrict__ outB) {
  __shared__ bf16_t Ald[64 * 64];
  __shared__ bf16_t Bld[64 * 64];
  int tid = threadIdx.x, lane = tid & 63, w = tid >> 6;
  int quad = lane >> 4, col = lane & 15;
  int m0 = blockIdx.y * 64, n0 = blockIdx.x * 64;
  int e = 0, ks = 0, kStart = 0, off = 0, cnt = Tc;
  if (MODE == 1) e = blockIdx.z;
  if (MODE == 2) { e = blockIdx.z >> 1; ks = blockIdx.z & 1; kStart = ks * (K / 2); }
  if (MODE != 0) {
    off = offs[e];
    cnt = offs[e + 1] - off;
    if (m0 >= cnt) return;
  }
  const bf16_t* B0 = Bt + (size_t)e * btStride;

  // A staging: wave w covers rows [w*16, w*16+16), 2 gll16 (8 rows each)
  const bf16_t* ga[2];
  bf16_t* la[2];
  for (int j = 0; j < 2; ++j) {
    int rbase = w * 16 + j * 8;
    int row = rbase + (lane >> 3);
    int ch = ((lane & 7) - row) & 7;
    int gm = m0 + row;
    int gmc = (gm < cnt) ? gm : (cnt - 1);
    int srow;
    if (MODE == 0) srow = gm;
    else if (MODE == 1) srow = perm[off + gmc];
    else srow = off + gmc;
    ga[j] = A + (size_t)srow * K + kStart + ch * 8;
    la[j] = Ald + rbase * 64;
  }
  // B staging: same shape
  const bf16_t* gb[2];
  bf16_t* lb[2];
  for (int j = 0; j < 2; ++j) {
    int rbase = w * 16 + j * 8;
    int row = rbase + (lane >> 3);
    int ch = ((lane & 7) - row) & 7;
    gb[j] = B0 + (size_t)(n0 + row) * K + kStart + ch * 8;
    lb[j] = Bld + rbase * 64;
  }

  int wr = (w >> 1) * 32, wc = (w & 1) * 32;
  int aoff[2], boff[2];
  for (int r = 0; r < 2; ++r) {
    int row = wr + r * 16 + col;
    aoff[r] = row * 64 + (((quad + row) & 7) << 3);
  }
  for (int c = 0; c < 2; ++c) {
    int row = wc + c * 16 + col;
    boff[c] = row * 64 + (((quad + row) & 7) << 3);
  }

  const f32x4 z4 = {0.f, 0.f, 0.f, 0.f};
  f32x4 acc[2][2];
  for (int r = 0; r < 2; ++r)
    for (int c = 0; c < 2; ++c) acc[r][c] = z4;

  for (int it = 0; it < kIters; ++it) {
    __syncthreads();
    gll16(ga[0], la[0]);
    gll16(ga[1], la[1]);
    gll16(gb[0], lb[0]);
    gll16(gb[1], lb[1]);
    ga[0] += 64; ga[1] += 64; gb[0] += 64; gb[1] += 64;
    __syncthreads();
    for (int kk = 0; kk < 2; ++kk) {
      bf16x8 af[2], bv[2];
      for (int r = 0; r < 2; ++r) af[r] = *(const bf16x8*)(Ald + (aoff[r] ^ (kk << 5)));
      for (int c = 0; c < 2; ++c) bv[c] = *(const bf16x8*)(Bld + (boff[c] ^ (kk << 5)));
      for (int r = 0; r < 2; ++r)
        for (int c = 0; c < 2; ++c)
          acc[r][c] = __builtin_amdgcn_mfma_f32_16x16x32_bf16(af[r], bv[c], acc[r][c], 0, 0, 0);
    }
  }

  for (int r = 0; r < 2; ++r)
    for (int c = 0; c < 2; ++c) {
      int mloc = wr + r * 16 + quad * 4;
      int n = n0 + wc + c * 16 + col;
      for (int i = 0; i < 4; ++i) {
        int gm = m0 + mloc + i;
        float av = acc[r][c][i];
        if (MODE == 0) {
          float bias = (n < 768) ? bqp[n] : (n < 1536) ? bkp[n - 768] : bvp[n - 1536];
          outB[(size_t)gm * N + n] = (bf16_t)(av + bias);
        } else if (MODE == 1) {
          if (gm < cnt) {
            float v = av + biasE[(size_t)e * biasStride + n];
            float u = v * (0.7978845608f + 0.0356774081f * v * v);
            float t = 1.f - 2.f / (1.f + __expf(2.f * u));
            outB[(size_t)(off + gm) * N + n] = (bf16_t)(0.5f * v * (1.f + t));
          }
        } else {
          if (gm < cnt) {
            int tok = perm[off + gm];
            outF[(size_t)ks * Tc * Hc + (size_t)tok * N + n] = av;
          }
        }
      }
    }
}

// ---------------------------------------------------------------- attention
__global__ __launch_bounds__(256) void attn_k(const bf16_t* __restrict__ qkv,
                                              const int* __restrict__ np,
                                              float* __restrict__ x) {
  __shared__ bf16_t Kld[256 * 64];  // reused as P after scores
  __shared__ bf16_t Vt[64 * 256];   // V transposed [d][s], swizzled
  int tid = threadIdx.x, lane = tid & 63, w = tid >> 6;
  int qt = blockIdx.x;
  int b = blockIdx.y / NHc, h = blockIdx.y % NHc;

  for (int j = 0; j < 8; ++j) {
    int rbase = w * 64 + j * 8;
    int row = rbase + (lane >> 3);
    int oc = ((lane & 7) - row) & 7;
    const bf16_t* gp = qkv + ((size_t)(b * 256 + row)) * 2304 + 768 + h * 64 + oc * 8;
    gll16(gp, Kld + rbase * 64);
  }
  {
    int s = tid, shi = s >> 3, slo = s & 7;
    const uint4* vs = (const uint4*)(qkv + ((size_t)(b * 256 + s)) * 2304 + 1536 + h * 64);
    for (int cc = 0; cc < 8; ++cc) {
      uint4 pk = vs[cc];
      const bf16_t* pv = (const bf16_t*)&pk;
      for (int jj = 0; jj < 8; ++jj) {
        int d = cc * 8 + jj;
        Vt[d * 256 + ((shi + d) & 31) * 8 + slo] = pv[jj];
      }
    }
  }
  int quad = lane >> 4, col = lane & 15;
  float madd[16];
  for (int nt = 0; nt < 16; ++nt)
    madd[nt] = (np[b * 256 + nt * 16 + col] != 0) ? 0.f : -10000.f;
  int qrow = qt * 64 + w * 16 + col;
  const bf16_t* qb = qkv + ((size_t)(b * 256 + qrow)) * 2304 + h * 64;
  bf16x8 qf0 = *(const bf16x8*)(qb + quad * 8);
  bf16x8 qf1 = *(const bf16x8*)(qb + 32 + quad * 8);
  __syncthreads();

  const f32x4 z4 = {0.f, 0.f, 0.f, 0.f};
  f32x4 sc[16];
  for (int nt = 0; nt < 16; ++nt) {
    int row = nt * 16 + col;
    bf16x8 k0 = *(const bf16x8*)(Kld + row * 64 + (((0 + quad + row) & 7) << 3));
    bf16x8 k1 = *(const bf16x8*)(Kld + row * 64 + (((4 + quad + row) & 7) << 3));
    f32x4 z = z4;
    z = __builtin_amdgcn_mfma_f32_16x16x32_bf16(qf0, k0, z, 0, 0, 0);
    z = __builtin_amdgcn_mfma_f32_16x16x32_bf16(qf1, k1, z, 0, 0, 0);
    sc[nt] = z;
  }
  for (int nt = 0; nt < 16; ++nt) {
    float a = madd[nt];
    sc[nt][0] += a; sc[nt][1] += a; sc[nt][2] += a; sc[nt][3] += a;
  }
  float pm[4], rl[4];
  for (int i = 0; i < 4; ++i) {
    float m = -1e30f;
    for (int nt = 0; nt < 16; ++nt) m = fmaxf(m, sc[nt][i]);
    for (int o = 1; o < 16; o <<= 1) m = fmaxf(m, __shfl_xor(m, o));
    float ssum = 0.f;
    for (int nt = 0; nt < 16; ++nt) ssum += __expf(sc[nt][i] - m);
    for (int o = 1; o < 16; o <<= 1) ssum += __shfl_xor(ssum, o);
    pm[i] = m;
    rl[i] = 1.f / ssum;
  }
  __syncthreads();
  bf16_t* Pb = Kld + w * 4096;
  for (int nt = 0; nt < 16; ++nt)
    for (int i = 0; i < 4; ++i) {
      int prow = quad * 4 + i;
      int key = nt * 16 + col;
      Pb[prow * 256 + (((key >> 3) + prow) & 31) * 8 + (key & 7)] =
          (bf16_t)__expf(sc[nt][i] - pm[i]);
    }
  __syncthreads();
  f32x4 oacc[4];
  for (int i = 0; i < 4; ++i) oacc[i] = z4;
  for (int kk2 = 0; kk2 < 8; ++kk2) {
    bf16x8 pa = *(const bf16x8*)(Pb + col * 256 + (((kk2 * 4 + quad + col) & 31) << 3));
    for (int nt2 = 0; nt2 < 4; ++nt2) {
      int d = nt2 * 16 + col;
      bf16x8 bv8 = *(const bf16x8*)(Vt + d * 256 + (((kk2 * 4 + quad + d) & 31) << 3));
      oacc[nt2] = __builtin_amdgcn_mfma_f32_16x16x32_bf16(pa, bv8, oacc[nt2], 0, 0, 0);
    }
  }
  for (int nt2 = 0; nt2 < 4; ++nt2)
    for (int i = 0; i < 4; ++i) {
      size_t o = ((size_t)(b * 256 + qt * 64 + w * 16 + quad * 4 + i)) * Hc + h * 64 + nt2 * 16 + col;
      x[o] += oacc[nt2][i] * rl[i];
    }
}

// ---------------------------------------------------------------- combine partials + residual + b2 + permute
__global__ __launch_bounds__(256) void combine_k(const float* __restrict__ x0,
                                                 const float* __restrict__ pbuf,
                                                 const float* __restrict__ b2l,
                                                 const int* __restrict__ ntp,
                                                 const int* __restrict__ np,
                                                 float* __restrict__ dst) {
  int i = blockIdx.x * 256 + threadIdx.x;  // float4 index over 2048*192
  int t = i / 192, d = i - t * 192;
  int idx = np[t];
  float4 o;
  if (idx != 0) {
    int r = idx - 1;
    int e = ntp[r];
    size_t j = (size_t)r * 192 + d;
    float4 a = ((const float4*)x0)[j];
    float4 p0 = ((const float4*)pbuf)[j];
    float4 p1 = ((const float4*)pbuf)[(size_t)Tc * 192 + j];
    float4 bb = ((const float4*)(b2l + (size_t)e * Hc))[d];
    o.x = a.x + p0.x + p1.x + bb.x;
    o.y = a.y + p0.y + p1.y + bb.y;
    o.z = a.z + p0.z + p1.z + bb.z;
    o.w = a.w + p0.w + p1.w + bb.w;
  } else {
    o.x = o.y = o.z = o.w = 0.f;
  }
  ((float4*)dst)[i] = o;
}

// ---------------------------------------------------------------- host
extern "C" void kernel_launch(void* const* d_in, const int* in_sizes, int n_in,
                              void* d_out, int out_size, void* d_ws, size_t ws_size,
                              hipStream_t stream) {
  const float* x_in = (const float*)d_in[0];
  const int* note_pos = (const int*)d_in[1];
  const int* ntp = (const int*)d_in[2];
  const float* Wq = (const float*)d_in[3];
  const float* bq = (const float*)d_in[4];
  const float* Wk = (const float*)d_in[5];
  const float* bk = (const float*)d_in[6];
  const float* Wv = (const float*)d_in[7];
  const float* bv = (const float*)d_in[8];
  const float* ln1w = (const float*)d_in[9];
  const float* ln1b = (const float*)d_in[10];
  const float* ln2w = (const float*)d_in[11];
  const float* ln2b = (const float*)d_in[12];
  const float* W1 = (const float*)d_in[13];
  const float* b1 = (const float*)d_in[14];
  const float* W2 = (const float*)d_in[15];
  const float* b2 = (const float*)d_in[16];
  float* out = (float*)d_out;

  char* p = (char*)d_ws;
  auto carve = [&](size_t bytes) -> char* {
    char* r = p;
    p += (bytes + 255) & ~(size_t)255;
    return r;
  };
  float* xA = (float*)carve((size_t)Tc * Hc * 4);
  float* xB = (float*)carve((size_t)Tc * Hc * 4);
  float* pbuf = (float*)carve((size_t)2 * Tc * Hc * 4);
  bf16_t* h16 = (bf16_t*)carve((size_t)Tc * Hc * 2);
  bf16_t* big = (bf16_t*)carve((size_t)Tc * FFc * 2);  // union: qkv16 / act1
  bf16_t* qkv16 = big;
  bf16_t* act1 = big;
  bf16_t* wqkvt = (bf16_t*)carve((size_t)Lc * 2304 * 768 * 2);
  bf16_t* w1t = (bf16_t*)carve((size_t)Lc * NEc * FFc * Hc * 2);
  bf16_t* w2t = (bf16_t*)carve((size_t)Lc * NEc * Hc * FFc * 2);
  int* perm = (int*)carve(Tc * 4);
  int* offs = (int*)carve(64);

  prep_k<<<1 + Tc * Hc / 2 / 256, 256, 0, stream>>>(x_in, ntp, xA, perm, offs);
  tconv_all<<<864 + 4608 + 4608, 256, 0, stream>>>(Wq, Wk, Wv, W1, W2, wqkvt, w1t, w2t);

  float* xcur = xA;
  for (int l = 0; l < Lc; ++l) {
    float* xdst = (l == Lc - 1) ? out : xB;
    ln_k<<<Tc / 4, 256, 0, stream>>>(xcur, ln1w + l * Hc, ln1b + l * Hc, h16);
    gemm2<0><<<dim3(36, 32, 1), 256, 0, stream>>>(
        h16, wqkvt + (size_t)l * 2304 * 768, Hc, 2304, 12, 0L, 0L, perm, offs,
        bq + l * Hc, bk + l * Hc, bv + l * Hc, nullptr, nullptr, qkv16);
    attn_k<<<dim3(4, Bc * NHc), 256, 0, stream>>>(qkv16, note_pos, xcur);
    ln_k<<<Tc / 4, 256, 0, stream>>>(xcur, ln2w + l * Hc, ln2b + l * Hc, h16);
    gemm2<1><<<dim3(48, 32, NEc), 256, 0, stream>>>(
        h16, w1t + (size_t)l * NEc * FFc * Hc, Hc, FFc, 12, (long)FFc * Hc, (long)FFc,
        perm, offs, nullptr, nullptr, nullptr, b1 + (size_t)l * NEc * FFc, nullptr, act1);
    gemm2<2><<<dim3(12, 32, NEc * 2), 256, 0, stream>>>(
        act1, w2t + (size_t)l * NEc * Hc * FFc, FFc, Hc, 24, (long)Hc * FFc, 0L,
        perm, offs, nullptr, nullptr, nullptr, nullptr, pbuf, nullptr);
    combine_k<<<Tc * 192 / 256, 256, 0, stream>>>(xcur, pbuf, b2 + (size_t)l * NEc * Hc,
                                                  ntp, note_pos, xdst);
    float* tmp = xcur; xcur = xdst; xB = tmp;  // ping-pong
  }
}